// Round 8
// baseline (269.255 us; speedup 1.0000x reference)
//
#include <hip/hip_runtime.h>

#define VOCAB 32000
#define E 64
#define H 8
#define L 25
#define B 1000
#define T 512

#define CHUNK 8                      // timesteps per super-step
#define NCHUNK (T / CHUNK)           // 64
#define NSTEP (NCHUNK + L - 1)       // 88
#define THREADS 256

// Per-layer LDS: 2 parities * CHUNK*8 floats = 128, padded to 132 (stride 4
// banks). Two batch buffers, each L*132 floats.
#define LAYER_STRIDE 132
#define BATCH_FLOATS (L * LAYER_STRIDE)      // 3300 floats
#define LDS_FLOATS (2 * BATCH_FLOATS)        // 26.4 KB

typedef float v2f __attribute__((ext_vector_type(2)));

// ---------------- phase 1: proj_table[v][j] = sum_k embedding[v][k] * W0[k][j]
__global__ __launch_bounds__(256) void proj_kernel(
    const float* __restrict__ emb, const float* __restrict__ w0,
    float* __restrict__ ptab)
{
    __shared__ float w0s[E * H];
    int tid = threadIdx.x;
    w0s[tid] = w0[tid];
    w0s[tid + 256] = w0[tid + 256];
    __syncthreads();

    int r = blockIdx.x * 256 + tid;
    if (r >= VOCAB) return;
    const float4* e4 = (const float4*)(emb + r * E);
    const v2f* w2 = (const v2f*)w0s;      // w2[k*4+p] = {W[k][2p], W[k][2p+1]}
    v2f a0 = {0.f, 0.f}, a1 = {0.f, 0.f}, a2 = {0.f, 0.f}, a3 = {0.f, 0.f};
#pragma unroll
    for (int k4 = 0; k4 < E / 4; ++k4) {
        float4 v = e4[k4];
        int kb = k4 * 16;
        a0 += (v2f){v.x, v.x} * w2[kb + 0];  a1 += (v2f){v.x, v.x} * w2[kb + 1];
        a2 += (v2f){v.x, v.x} * w2[kb + 2];  a3 += (v2f){v.x, v.x} * w2[kb + 3];
        a0 += (v2f){v.y, v.y} * w2[kb + 4];  a1 += (v2f){v.y, v.y} * w2[kb + 5];
        a2 += (v2f){v.y, v.y} * w2[kb + 6];  a3 += (v2f){v.y, v.y} * w2[kb + 7];
        a0 += (v2f){v.z, v.z} * w2[kb + 8];  a1 += (v2f){v.z, v.z} * w2[kb + 9];
        a2 += (v2f){v.z, v.z} * w2[kb + 10]; a3 += (v2f){v.z, v.z} * w2[kb + 11];
        a0 += (v2f){v.w, v.w} * w2[kb + 12]; a1 += (v2f){v.w, v.w} * w2[kb + 13];
        a2 += (v2f){v.w, v.w} * w2[kb + 14]; a3 += (v2f){v.w, v.w} * w2[kb + 15];
    }
    float4* o4 = (float4*)(ptab + r * 8);
    o4[0] = (float4){a0.x, a0.y, a1.x, a1.y};
    o4[1] = (float4){a2.x, a2.y, a3.x, a3.y};
}

// tanh(x) = 1 - 2/(e^{2x}+1), raw HW ops: mul + v_exp + add + v_rcp + fma.
__device__ __forceinline__ float fast_tanh(float x) {
    float t = __builtin_amdgcn_exp2f(x * 2.8853900817779268f);  // e^{2x}
    float r = __builtin_amdgcn_rcpf(1.0f + t);
    return __builtin_fmaf(-2.0f, r, 1.0f);
}

// 8-lane butterfly, ALL DPP (no LDS pipe). Lane mapping puts the unit xor-4
// exchange at lane-xor-8 = ROW_ROR:8 within a 16-lane row. (HW-verified R4/R7.)
__device__ __forceinline__ float dpp_xor1(float x) {   // quad_perm [1,0,3,2]
    return __int_as_float(__builtin_amdgcn_mov_dpp(__float_as_int(x), 0xB1, 0xF, 0xF, true));
}
__device__ __forceinline__ float dpp_xor2(float x) {   // quad_perm [2,3,0,1]
    return __int_as_float(__builtin_amdgcn_mov_dpp(__float_as_int(x), 0x4E, 0xF, 0xF, true));
}
__device__ __forceinline__ float dpp_xor8(float x) {   // ROW_ROR:8 == lane^8 in row
    return __int_as_float(__builtin_amdgcn_mov_dpp(__float_as_int(x), 0x128, 0xF, 0xF, true));
}

// ---------------- phase 2: layer-pipelined recurrence, 2 batches per lane.
// Lane mapping: row = tid>>4; unit j at pos (j&3)+((j>>2)<<3)+(g&1)*4;
// layer g = 2*row + ((pos>>2)&1). Weights shared across the 2 batch chains.
__global__ __launch_bounds__(THREADS) void rnn_recur(
    const int*   __restrict__ x,      // [B,T]
    const float* __restrict__ h0,     // [L,B,H]
    const float* __restrict__ wrest,  // [L-1,H,H]
    const float* __restrict__ whh_g,  // [L,H,H]
    const float* __restrict__ bh,     // [L,H]
    const float* __restrict__ why,    // [H]
    const float* __restrict__ by,     // [1]
    const float* __restrict__ ptab,   // [VOCAB,H]
    float*       __restrict__ out)    // [B] logits ++ [L,B,H] h_last
{
    __shared__ __align__(16) float buf[LDS_FLOATS];

    const int tid = threadIdx.x;
    const int row = tid >> 4;
    const int lp  = tid & 15;
    const int j   = (lp & 3) | ((lp >> 3) << 2);   // unit
    const int g   = row * 2 + ((lp >> 2) & 1);     // layer
    const bool active = g < L;
    const int gc  = active ? g : 0;
    const int b0 = blockIdx.x * 2;
    const int b1 = b0 + 1;

    // weights permuted so slot m multiplies h_{j^m} (shared by both batches)
    v2f wh01 = {0.f, 0.f}, wh23 = {0.f, 0.f}, wh45 = {0.f, 0.f}, wh67 = {0.f, 0.f};
    v2f wx01 = {0.f, 0.f}, wx23 = {0.f, 0.f}, wx45 = {0.f, 0.f}, wx67 = {0.f, 0.f};
    v2f hA01 = {0.f, 0.f}, hA23 = {0.f, 0.f}, hA45 = {0.f, 0.f}, hA67 = {0.f, 0.f};
    v2f hB01 = {0.f, 0.f}, hB23 = {0.f, 0.f}, hB45 = {0.f, 0.f}, hB67 = {0.f, 0.f};
    float bias = 0.f;

    float* mybufA = &buf[gc * LAYER_STRIDE];
    float* mybufB = mybufA + BATCH_FLOATS;
    const float* prevbufA = (gc > 0) ? (mybufA - LAYER_STRIDE) : mybufA;
    const float* prevbufB = prevbufA + BATCH_FLOATS;

    if (active) {
        const float* whL = whh_g + g * 64;
        wh01 = (v2f){whL[(j ^ 0) * 8 + j], whL[(j ^ 1) * 8 + j]};
        wh23 = (v2f){whL[(j ^ 2) * 8 + j], whL[(j ^ 3) * 8 + j]};
        wh45 = (v2f){whL[(j ^ 4) * 8 + j], whL[(j ^ 5) * 8 + j]};
        wh67 = (v2f){whL[(j ^ 6) * 8 + j], whL[(j ^ 7) * 8 + j]};
        if (g > 0) {
            const float* wxL = wrest + (g - 1) * 64;
            wx01 = (v2f){wxL[0 * 8 + j], wxL[1 * 8 + j]};
            wx23 = (v2f){wxL[2 * 8 + j], wxL[3 * 8 + j]};
            wx45 = (v2f){wxL[4 * 8 + j], wxL[5 * 8 + j]};
            wx67 = (v2f){wxL[6 * 8 + j], wxL[7 * 8 + j]};
        }
        bias = bh[g * 8 + j];
        const float* hA0p = h0 + (g * B + b0) * H;
        const float* hB0p = h0 + (g * B + b1) * H;
        hA01 = (v2f){hA0p[j ^ 0], hA0p[j ^ 1]};
        hA23 = (v2f){hA0p[j ^ 2], hA0p[j ^ 3]};
        hA45 = (v2f){hA0p[j ^ 4], hA0p[j ^ 5]};
        hA67 = (v2f){hA0p[j ^ 6], hA0p[j ^ 7]};
        hB01 = (v2f){hB0p[j ^ 0], hB0p[j ^ 1]};
        hB23 = (v2f){hB0p[j ^ 2], hB0p[j ^ 3]};
        hB45 = (v2f){hB0p[j ^ 4], hB0p[j ^ 5]};
        hB67 = (v2f){hB0p[j ^ 6], hB0p[j ^ 7]};
    }

    const int xbaseA = b0 * T;
    const int xbaseB = b1 * T;
    float pvA[CHUNK], pvB[CHUNK];
    if (active && g == 0) {
#pragma unroll
        for (int ct = 0; ct < CHUNK; ++ct) {
            pvA[ct] = ptab[x[xbaseA + ct] * H + j];
            pvB[ct] = ptab[x[xbaseB + ct] * H + j];
        }
    }

    for (int s = 0; s < NSTEP; ++s) {
        const int c = s - g;
        if (active && (unsigned)c < (unsigned)NCHUNK) {
            const int p = c & 1;
            float* wptrA = mybufA + p * (CHUNK * 8);
            float* wptrB = mybufB + p * (CHUNK * 8);
            const float4* ip4A = (const float4*)(prevbufA + p * (CHUNK * 8));
            const float4* ip4B = (const float4*)(prevbufB + p * (CHUNK * 8));

            int4 tA0, tA1, tB0, tB1;           // next-chunk tokens (layer 0)
            const bool pf = (g == 0) && (c + 1 < NCHUNK);
            if (pf) {
                const int4* xpA = (const int4*)(x + xbaseA + (c + 1) * CHUNK);
                const int4* xpB = (const int4*)(x + xbaseB + (c + 1) * CHUNK);
                tA0 = xpA[0]; tA1 = xpA[1];
                tB0 = xpB[0]; tB1 = xpB[1];
            }

#pragma unroll
            for (int ct = 0; ct < CHUNK; ++ct) {
                v2f accA, accA2, accB, accB2;
                if (g == 0) {
                    accA  = (v2f){pvA[ct] + bias, 0.f};
                    accA2 = (v2f){0.f, 0.f};
                    accB  = (v2f){pvB[ct] + bias, 0.f};
                    accB2 = (v2f){0.f, 0.f};
                } else {
                    float4 iaA = ip4A[2 * ct];
                    float4 ibA = ip4A[2 * ct + 1];
                    float4 iaB = ip4B[2 * ct];
                    float4 ibB = ip4B[2 * ct + 1];
                    accA   = (v2f){bias, 0.f};
                    accA  += (v2f){iaA.x, iaA.y} * wx01;
                    accA2  = (v2f){iaA.z, iaA.w} * wx23;
                    accA  += (v2f){ibA.x, ibA.y} * wx45;
                    accA2 += (v2f){ibA.z, ibA.w} * wx67;
                    accB   = (v2f){bias, 0.f};
                    accB  += (v2f){iaB.x, iaB.y} * wx01;
                    accB2  = (v2f){iaB.z, iaB.w} * wx23;
                    accB  += (v2f){ibB.x, ibB.y} * wx45;
                    accB2 += (v2f){ibB.z, ibB.w} * wx67;
                }
                accA  += hA01 * wh01;
                accA2 += hA23 * wh23;
                accA  += hA45 * wh45;
                accA2 += hA67 * wh67;
                accB  += hB01 * wh01;
                accB2 += hB23 * wh23;
                accB  += hB45 * wh45;
                accB2 += hB67 * wh67;
                v2f atA = accA + accA2;
                v2f atB = accB + accB2;
                float hnA = fast_tanh(atA.x + atA.y);
                float hnB = fast_tanh(atB.x + atB.y);

                if (g < L - 1) {
                    wptrA[ct * 8 + j] = hnA;    // cross-layer handoff only
                    wptrB[ct * 8 + j] = hnB;
                }

                // all-DPP register all-gather, both batches (independent chains)
                float oA1 = dpp_xor1(hnA);
                float oB1 = dpp_xor1(hnB);
                float qA0 = dpp_xor2(hnA);
                float qB0 = dpp_xor2(hnB);
                float qA1 = dpp_xor2(oA1);
                float qB1 = dpp_xor2(oB1);
                hA01 = (v2f){hnA, oA1};
                hB01 = (v2f){hnB, oB1};
                hA23 = (v2f){qA0, qA1};
                hB23 = (v2f){qB0, qB1};
                hA45 = (v2f){dpp_xor8(hnA), dpp_xor8(oA1)};
                hB45 = (v2f){dpp_xor8(hnB), dpp_xor8(oB1)};
                hA67 = (v2f){dpp_xor8(qA0), dpp_xor8(qA1)};
                hB67 = (v2f){dpp_xor8(qB0), dpp_xor8(qB1)};
            }

            if (pf) {
                pvA[0] = ptab[tA0.x * H + j];
                pvA[1] = ptab[tA0.y * H + j];
                pvA[2] = ptab[tA0.z * H + j];
                pvA[3] = ptab[tA0.w * H + j];
                pvA[4] = ptab[tA1.x * H + j];
                pvA[5] = ptab[tA1.y * H + j];
                pvA[6] = ptab[tA1.z * H + j];
                pvA[7] = ptab[tA1.w * H + j];
                pvB[0] = ptab[tB0.x * H + j];
                pvB[1] = ptab[tB0.y * H + j];
                pvB[2] = ptab[tB0.z * H + j];
                pvB[3] = ptab[tB0.w * H + j];
                pvB[4] = ptab[tB1.x * H + j];
                pvB[5] = ptab[tB1.y * H + j];
                pvB[6] = ptab[tB1.z * H + j];
                pvB[7] = ptab[tB1.w * H + j];
            }

            if (c == NCHUNK - 1) {
                out[B + (g * B + b0) * H + j] = hA01.x;   // h_last
                out[B + (g * B + b1) * H + j] = hB01.x;
                if (g == L - 1) {                         // logits
                    float lgA = by[0], lgB = by[0];
                    lgA += hA01.x * why[j]     + hA01.y * why[j ^ 1];
                    lgB += hB01.x * why[j]     + hB01.y * why[j ^ 1];
                    lgA += hA23.x * why[j ^ 2] + hA23.y * why[j ^ 3];
                    lgB += hB23.x * why[j ^ 2] + hB23.y * why[j ^ 3];
                    lgA += hA45.x * why[j ^ 4] + hA45.y * why[j ^ 5];
                    lgB += hB45.x * why[j ^ 4] + hB45.y * why[j ^ 5];
                    lgA += hA67.x * why[j ^ 6] + hA67.y * why[j ^ 7];
                    lgB += hB67.x * why[j ^ 6] + hB67.y * why[j ^ 7];
                    if (j == 0) {
                        out[b0] = lgA;
                        out[b1] = lgB;
                    }
                }
            }
        }
        __syncthreads();
    }
}

extern "C" void kernel_launch(void* const* d_in, const int* in_sizes, int n_in,
                              void* d_out, int out_size, void* d_ws, size_t ws_size,
                              hipStream_t stream) {
    const int*   x     = (const int*)d_in[0];
    const float* h0    = (const float*)d_in[1];
    const float* emb   = (const float*)d_in[2];
    const float* w0    = (const float*)d_in[3];
    const float* wrest = (const float*)d_in[4];
    const float* whh   = (const float*)d_in[5];
    const float* bh    = (const float*)d_in[6];
    const float* why   = (const float*)d_in[7];
    const float* by    = (const float*)d_in[8];
    float* out  = (float*)d_out;
    float* ptab = (float*)d_ws;                       // 1 MB scratch

    hipLaunchKernelGGL(proj_kernel, dim3((VOCAB + 255) / 256), dim3(256),
                       0, stream, emb, w0, ptab);
    hipLaunchKernelGGL(rnn_recur, dim3(B / 2), dim3(THREADS),
                       0, stream, x, h0, wrest, whh, bh, why, by, ptab, out);
}

// Round 9
// 221.686 us; speedup vs baseline: 1.2146x; 1.2146x over previous
//
#include <hip/hip_runtime.h>

#define VOCAB 32000
#define E 64
#define H 8
#define L 25
#define B 1000
#define T 512

#define CHUNK 8                      // timesteps per super-step
#define NCHUNK (T / CHUNK)           // 64
#define NSTEP (NCHUNK + L - 1)       // 88
#define THREADS 256

// Per-layer LDS: 2 parities * CHUNK*8 floats = 128, padded to 132.
#define LAYER_STRIDE 132
#define LDS_FLOATS (L * LAYER_STRIDE)    // 3300 floats = 13.2 KB

#define SCALE 2.8853900817779268f        // 2*log2(e): tanh(x)=1-2/(1+exp2(SC*x))

typedef float v2f __attribute__((ext_vector_type(2)));

// ---------------- phase 1: ptab[v][j] = SCALE * (emb[v]·W0[:,j] + bh0[j])
__global__ __launch_bounds__(256) void proj_kernel(
    const float* __restrict__ emb, const float* __restrict__ w0,
    const float* __restrict__ bh, float* __restrict__ ptab)
{
    __shared__ float w0s[E * H];
    int tid = threadIdx.x;
    w0s[tid] = w0[tid];
    w0s[tid + 256] = w0[tid + 256];
    __syncthreads();

    int r = blockIdx.x * 256 + tid;
    if (r >= VOCAB) return;
    const float4* e4 = (const float4*)(emb + r * E);
    const v2f* w2 = (const v2f*)w0s;      // w2[k*4+p] = {W[k][2p], W[k][2p+1]}
    v2f a0 = {0.f, 0.f}, a1 = {0.f, 0.f}, a2 = {0.f, 0.f}, a3 = {0.f, 0.f};
#pragma unroll
    for (int k4 = 0; k4 < E / 4; ++k4) {
        float4 v = e4[k4];
        int kb = k4 * 16;
        a0 += (v2f){v.x, v.x} * w2[kb + 0];  a1 += (v2f){v.x, v.x} * w2[kb + 1];
        a2 += (v2f){v.x, v.x} * w2[kb + 2];  a3 += (v2f){v.x, v.x} * w2[kb + 3];
        a0 += (v2f){v.y, v.y} * w2[kb + 4];  a1 += (v2f){v.y, v.y} * w2[kb + 5];
        a2 += (v2f){v.y, v.y} * w2[kb + 6];  a3 += (v2f){v.y, v.y} * w2[kb + 7];
        a0 += (v2f){v.z, v.z} * w2[kb + 8];  a1 += (v2f){v.z, v.z} * w2[kb + 9];
        a2 += (v2f){v.z, v.z} * w2[kb + 10]; a3 += (v2f){v.z, v.z} * w2[kb + 11];
        a0 += (v2f){v.w, v.w} * w2[kb + 12]; a1 += (v2f){v.w, v.w} * w2[kb + 13];
        a2 += (v2f){v.w, v.w} * w2[kb + 14]; a3 += (v2f){v.w, v.w} * w2[kb + 15];
    }
    float4 b0 = *(const float4*)bh;        // layer-0 bias [0..3]
    float4 b1 = *(const float4*)(bh + 4);  // layer-0 bias [4..7]
    float4* o4 = (float4*)(ptab + r * 8);
    o4[0] = (float4){(a0.x + b0.x) * SCALE, (a0.y + b0.y) * SCALE,
                     (a1.x + b0.z) * SCALE, (a1.y + b0.w) * SCALE};
    o4[1] = (float4){(a2.x + b1.x) * SCALE, (a2.y + b1.y) * SCALE,
                     (a3.x + b1.z) * SCALE, (a3.y + b1.w) * SCALE};
}

// 8-lane butterfly, ALL DPP (no LDS pipe). Lane mapping puts the unit xor-4
// exchange at lane-xor-8 = ROW_ROR:8 within a 16-lane row. (HW-verified.)
__device__ __forceinline__ float dpp_xor1(float x) {   // quad_perm [1,0,3,2]
    return __int_as_float(__builtin_amdgcn_mov_dpp(__float_as_int(x), 0xB1, 0xF, 0xF, true));
}
__device__ __forceinline__ float dpp_xor2(float x) {   // quad_perm [2,3,0,1]
    return __int_as_float(__builtin_amdgcn_mov_dpp(__float_as_int(x), 0x4E, 0xF, 0xF, true));
}
__device__ __forceinline__ float dpp_xor8(float x) {   // ROW_ROR:8 == lane^8 in row
    return __int_as_float(__builtin_amdgcn_mov_dpp(__float_as_int(x), 0x128, 0xF, 0xF, true));
}

// ---------------- phase 2: layer-pipelined recurrence, BRANCHLESS body.
// Lane mapping: row = tid>>4; unit j at pos (j&3)+((j>>2)<<3)+(g&1)*4;
// layer g = 2*row + ((pos>>2)&1). Weights pre-scaled by SCALE; for g==0
// wx=0 and pv[] carries ptab (scaled, biased); for g>0 pv[] = scaled bias.
__global__ __launch_bounds__(THREADS) void rnn_recur(
    const int*   __restrict__ x,      // [B,T]
    const float* __restrict__ h0,     // [L,B,H]
    const float* __restrict__ wrest,  // [L-1,H,H]
    const float* __restrict__ whh_g,  // [L,H,H]
    const float* __restrict__ bh,     // [L,H]
    const float* __restrict__ why,    // [H]
    const float* __restrict__ by,     // [1]
    const float* __restrict__ ptab,   // [VOCAB,H] pre-scaled+biased
    float*       __restrict__ out)    // [B] logits ++ [L,B,H] h_last
{
    __shared__ __align__(16) float buf[LDS_FLOATS];

    const int tid = threadIdx.x;
    // zero-init so layer-0's dummy input reads are finite (0 * wx0 = 0)
    for (int k = tid; k < LDS_FLOATS; k += THREADS) buf[k] = 0.f;

    const int row = tid >> 4;
    const int lp  = tid & 15;
    const int j   = (lp & 3) | ((lp >> 3) << 2);   // unit
    const int g   = row * 2 + ((lp >> 2) & 1);     // layer
    const bool active = g < L;
    const int gc  = active ? g : 0;
    const int b = blockIdx.x;

    v2f wh01 = {0.f, 0.f}, wh23 = {0.f, 0.f}, wh45 = {0.f, 0.f}, wh67 = {0.f, 0.f};
    v2f wx01 = {0.f, 0.f}, wx23 = {0.f, 0.f}, wx45 = {0.f, 0.f}, wx67 = {0.f, 0.f};
    v2f h01  = {0.f, 0.f}, h23  = {0.f, 0.f}, h45  = {0.f, 0.f}, h67  = {0.f, 0.f};

    float* mybuf = &buf[gc * LAYER_STRIDE];
    const float* prevbuf = (gc > 0) ? (mybuf - LAYER_STRIDE) : mybuf;

    float pv[CHUNK];
    if (active) {
        const float* whL = whh_g + g * 64;
        wh01 = (v2f){whL[(j ^ 0) * 8 + j], whL[(j ^ 1) * 8 + j]} * SCALE;
        wh23 = (v2f){whL[(j ^ 2) * 8 + j], whL[(j ^ 3) * 8 + j]} * SCALE;
        wh45 = (v2f){whL[(j ^ 4) * 8 + j], whL[(j ^ 5) * 8 + j]} * SCALE;
        wh67 = (v2f){whL[(j ^ 6) * 8 + j], whL[(j ^ 7) * 8 + j]} * SCALE;
        if (g > 0) {
            const float* wxL = wrest + (g - 1) * 64;
            wx01 = (v2f){wxL[0 * 8 + j], wxL[1 * 8 + j]} * SCALE;
            wx23 = (v2f){wxL[2 * 8 + j], wxL[3 * 8 + j]} * SCALE;
            wx45 = (v2f){wxL[4 * 8 + j], wxL[5 * 8 + j]} * SCALE;
            wx67 = (v2f){wxL[6 * 8 + j], wxL[7 * 8 + j]} * SCALE;
        }
        const float* h0p = h0 + (g * B + b) * H;
        h01 = (v2f){h0p[j ^ 0], h0p[j ^ 1]};
        h23 = (v2f){h0p[j ^ 2], h0p[j ^ 3]};
        h45 = (v2f){h0p[j ^ 4], h0p[j ^ 5]};
        h67 = (v2f){h0p[j ^ 6], h0p[j ^ 7]};
        float bs = bh[g * 8 + j] * SCALE;    // scaled bias (g>0 path)
#pragma unroll
        for (int ct = 0; ct < CHUNK; ++ct) pv[ct] = bs;
    }

    const int xbase = b * T;
    if (active && g == 0) {
#pragma unroll
        for (int ct = 0; ct < CHUNK; ++ct)
            pv[ct] = ptab[x[xbase + ct] * H + j];
    }
    __syncthreads();

    for (int s = 0; s < NSTEP; ++s) {
        const int c = s - g;
        if (active && (unsigned)c < (unsigned)NCHUNK) {
            const int p = c & 1;
            float* wptr = mybuf + p * (CHUNK * 8);
            const float4* ip4 = (const float4*)(prevbuf + p * (CHUNK * 8));

            int4 t0, t1;                       // next-chunk tokens (layer 0)
            const bool pf = (g == 0) && (c + 1 < NCHUNK);
            if (pf) {
                const int4* xp4 = (const int4*)(x + xbase + (c + 1) * CHUNK);
                t0 = xp4[0];
                t1 = xp4[1];
            }

            float4 ia = ip4[0], ib = ip4[1];
#pragma unroll
            for (int ct = 0; ct < CHUNK; ++ct) {
                float4 ian = ia, ibn = ib;
                if (ct < CHUNK - 1) {          // read-ahead (before this ct's write)
                    ian = ip4[2 * ct + 2];
                    ibn = ip4[2 * ct + 3];
                }
                v2f r0 = (v2f){ia.x, ia.y} * wx01;
                v2f r1 = (v2f){ia.z, ia.w} * wx23;
                r0 += (v2f){ib.x, ib.y} * wx45;
                r1 += (v2f){ib.z, ib.w} * wx67;
                r0 += h01 * wh01;
                r1 += h23 * wh23;
                r0 += h45 * wh45;
                r1 += h67 * wh67;
                v2f at = r0 + r1;
                float arg = at.x + at.y + pv[ct];   // pre-scaled
                float t = __builtin_amdgcn_exp2f(arg);
                float rc = __builtin_amdgcn_rcpf(1.0f + t);
                float hn = __builtin_fmaf(-2.0f, rc, 1.0f);

                wptr[ct * 8 + j] = hn;         // cross-layer handoff

                float o1 = dpp_xor1(hn);
                float q0 = dpp_xor2(hn);
                float q1 = dpp_xor2(o1);
                h01 = (v2f){hn, o1};
                h23 = (v2f){q0, q1};
                h45 = (v2f){dpp_xor8(hn), dpp_xor8(o1)};
                h67 = (v2f){dpp_xor8(q0), dpp_xor8(q1)};

                ia = ian;
                ib = ibn;
            }

            if (pf) {
                pv[0] = ptab[t0.x * H + j];
                pv[1] = ptab[t0.y * H + j];
                pv[2] = ptab[t0.z * H + j];
                pv[3] = ptab[t0.w * H + j];
                pv[4] = ptab[t1.x * H + j];
                pv[5] = ptab[t1.y * H + j];
                pv[6] = ptab[t1.z * H + j];
                pv[7] = ptab[t1.w * H + j];
            }

            if (c == NCHUNK - 1) {
                out[B + (g * B + b) * H + j] = h01.x;   // h_last
                if (g == L - 1) {                       // logits
                    float lg = by[0];
                    lg += h01.x * why[j]     + h01.y * why[j ^ 1];
                    lg += h23.x * why[j ^ 2] + h23.y * why[j ^ 3];
                    lg += h45.x * why[j ^ 4] + h45.y * why[j ^ 5];
                    lg += h67.x * why[j ^ 6] + h67.y * why[j ^ 7];
                    if (j == 0) out[b] = lg;
                }
            }
        }
        __syncthreads();
    }
}

extern "C" void kernel_launch(void* const* d_in, const int* in_sizes, int n_in,
                              void* d_out, int out_size, void* d_ws, size_t ws_size,
                              hipStream_t stream) {
    const int*   x     = (const int*)d_in[0];
    const float* h0    = (const float*)d_in[1];
    const float* emb   = (const float*)d_in[2];
    const float* w0    = (const float*)d_in[3];
    const float* wrest = (const float*)d_in[4];
    const float* whh   = (const float*)d_in[5];
    const float* bh    = (const float*)d_in[6];
    const float* why   = (const float*)d_in[7];
    const float* by    = (const float*)d_in[8];
    float* out  = (float*)d_out;
    float* ptab = (float*)d_ws;                       // 1 MB scratch

    hipLaunchKernelGGL(proj_kernel, dim3((VOCAB + 255) / 256), dim3(256),
                       0, stream, emb, w0, bh, ptab);
    hipLaunchKernelGGL(rnn_recur, dim3(B), dim3(THREADS),
                       0, stream, x, h0, wrest, whh, bh, why, by, ptab, out);
}